// Round 10
// baseline (743.326 us; speedup 1.0000x reference)
//
#include <hip/hip_runtime.h>
#include <hip/hip_bf16.h>
#include <math.h>

#define B_  32
#define T_  2048
#define D_  512
#define V_  1024
#define K_  3

typedef __attribute__((ext_vector_type(8))) short   short8;
typedef __attribute__((ext_vector_type(4))) float   floatx4;

#define SCALE_H0 256.0f        // hidden0 fp8 scale (conv1 input)
#define SCALE_A  64.0f         // H1 activation fp8 scale (conv2 input)
#define SCALE_W  16.0f         // weight fp8 scale (both convs)
#define INV1 (1.0f/(SCALE_H0*SCALE_W))
#define INV2 (1.0f/(SCALE_A*SCALE_W))

// ---- output flat offsets (elements, fp32) ----
#define OFF0 0        // global_rate      [32]
#define OFF1 32       // summary_state    [32*512]
#define OFF2 16416    // residual_mean    [32]
#define OFF3 16448    // residual_var     [32]
#define OFF4 16480    // coverage         [32]
#define OFF5 16512    // mask             [32*2048]
#define OFF6 82048    // logdur           [32*2048]
#define OFF7 147584   // ref_residual     [32*2048]
#define OFF8 213120   // attn             [32*2048]
#define OFF9 278656   // prompt_role_fit  [32*2048]
#define OFF10 344192  // coeff_norm       [32]

// ---- workspace byte offsets (total 35,553,408 B < proven 36.34 MB) ----
#define WS_RR     0          // fp32 [32][2048]              262144 B
#define WS_SUP    262144     // fp32 [32]                       128 B
#define WS_PSUM   262272     // fp32 [32][512]                65536 B
#define WS_PSUMSQ 327808     // fp32 [32][512]                65536 B
#define WS_W1P    393344     // fp8  frag-packed conv1 w     786432 B
#define WS_W2P    1179776    // fp8  frag-packed conv2 w     786432 B
#define WS_H1     1966208    // fp8  [32][2050][512]       33587200 B

__device__ __forceinline__ float clampf(float v, float lo, float hi) {
    v = (v > lo) ? v : lo;
    return (v < hi) ? v : hi;
}
__device__ __forceinline__ float gelu_exact(float v) {
    return 0.5f * v * (1.0f + erff(v * 0.70710678118654752440f));
}
// tanh-form gelu: max |dev| vs exact ~4e-4 — far below fp8 quant noise.
__device__ __forceinline__ float gelu_fast(float x) {
    float u = 0.7978845608f * (x + 0.044715f * x * x * x);
    u = clampf(u, -9.0f, 9.0f);
    float t = __expf(2.0f * u);
    float th = (t - 1.0f) * __builtin_amdgcn_rcpf(t + 1.0f);
    return 0.5f * x * (1.0f + th);
}
__device__ __forceinline__ unsigned char f2fp8(float x) {
    int v = __builtin_amdgcn_cvt_pk_fp8_f32(x, x, 0, false);
    return (unsigned char)(v & 0xFF);
}
__device__ __forceinline__ int pk4fp8(float a, float b, float c, float d) {
    int p0 = __builtin_amdgcn_cvt_pk_fp8_f32(a, b, 0, false);
    int p1 = __builtin_amdgcn_cvt_pk_fp8_f32(c, d, 0, false);
    return (p1 << 16) | (p0 & 0xFFFF);
}

__device__ __forceinline__ float block_reduce_sum(float v, float* red, int tid) {
    __syncthreads();
    red[tid] = v;
    __syncthreads();
    for (int s = 128; s > 0; s >>= 1) {
        if (tid < s) red[tid] += red[tid + s];
        __syncthreads();
    }
    float r = red[0];
    __syncthreads();
    return r;
}

// ---------------------------------------------------------------------------
// Kernel 1 (R7 layout): prepack both conv weights into MFMA-fragment-linear
//   fp8 layout; zero psum/psumsq and H1 causal pad rows.
//  idx = ((s*32+ntg)*64+lane)*8+e  = w[col][kin][k],  s = k*16+ci,
//    col = ntg*16 + (lane&15), kin = ci*32 + (lane>>4)*8 + e
// ---------------------------------------------------------------------------
__global__ __launch_bounds__(256) void prepack_kernel(
    const float* __restrict__ w1, const float* __restrict__ w2,
    unsigned char* __restrict__ W1p, unsigned char* __restrict__ W2p,
    float* __restrict__ psum, unsigned char* __restrict__ H1buf)
{
    int pid = blockIdx.x * 256 + threadIdx.x;   // 0 .. 98303
    int lane = pid & 63;
    int ntg = (pid >> 6) & 31;
    int ci  = (pid >> 11) & 15;
    int k   = pid >> 15;                        // 0..2
    int col = ntg * 16 + (lane & 15);
    int kin = ci * 32 + (lane >> 4) * 8;

    unsigned char v1[8], v2[8];
    #pragma unroll
    for (int e = 0; e < 8; ++e) {
        size_t src = ((size_t)col * D_ + kin + e) * K_ + k;
        v1[e] = f2fp8(w1[src] * SCALE_W);
        v2[e] = f2fp8(w2[src] * SCALE_W);
    }
    *(double*)(W1p + (size_t)pid * 8) = *(double*)v1;
    *(double*)(W2p + (size_t)pid * 8) = *(double*)v2;

    if (pid < 32768) psum[pid] = 0.0f;          // psum + psumsq contiguous
    if (pid < 32768) {                          // zero 2 causal pad rows/batch
        int b = pid >> 10;
        int r = (pid >> 9) & 1;
        int d = pid & 511;
        H1buf[((size_t)b * 2050 + r) * 512 + d] = 0;
    }
}

// ---------------------------------------------------------------------------
// Kernel 2: per-batch stats — histogram-select exact median + T-wise outputs
// ---------------------------------------------------------------------------
#define NB 2048
#define HLO (-9.3f)
#define HSC ((float)NB / 10.05f)     // range [-9.3, 0.75]
__global__ __launch_bounds__(256) void stats_kernel(
    const float* __restrict__ dur, const float* __restrict__ maskp,
    float* __restrict__ rr_ws, float* __restrict__ sup_ws,
    float* __restrict__ out)
{
    int b = blockIdx.x;
    int tid = threadIdx.x;
    __shared__ int   hist[NB];
    __shared__ int   csum[256];
    __shared__ float red[256];
    __shared__ float cand[128];
    __shared__ float nsh, medsh;
    __shared__ int   sh_tb, sh_cb, sh_candn;

    const float* durb = dur + (size_t)b * T_;
    const float* mkb  = maskp + (size_t)b * T_;

    float ld[8], mk[8];
    int   bn[8];
    float cnt = 0.0f;
    #pragma unroll
    for (int i = 0; i < 8; ++i) hist[tid * 8 + i] = 0;
    __syncthreads();
    #pragma unroll
    for (int i = 0; i < 8; ++i) {
        int t = tid + i * 256;
        float m = clampf(mkb[t], 0.0f, 1.0f);
        float dv = durb[t];
        dv = (dv >= 1e-4f) ? dv : 1e-4f;
        float l = logf(dv) * m;
        ld[i] = l; mk[i] = m;
        int bin = (int)((l - HLO) * HSC);
        bin = (bin < 0) ? 0 : ((bin > NB - 1) ? NB - 1 : bin);
        bn[i] = bin;
        if (m > 0.5f) { cnt += 1.0f; atomicAdd(&hist[bin], 1); }
    }
    float n = block_reduce_sum(cnt, red, tid);   // barriers make hist visible
    if (tid == 0) { nsh = n; sh_candn = 0; medsh = 0.0f; }

    // chunk sums + inclusive scan (Hillis-Steele)
    {
        int cs = 0;
        #pragma unroll
        for (int i = 0; i < 8; ++i) cs += hist[tid * 8 + i];
        csum[tid] = cs;
        __syncthreads();
        for (int off = 1; off < 256; off <<= 1) {
            int v = (tid >= off) ? csum[tid - off] : 0;
            __syncthreads();
            csum[tid] += v;
            __syncthreads();
        }
    }
    int ni = (int)(n + 0.5f);
    int k  = (ni > 0) ? ((ni - 1) >> 1) : 0;     // 0-indexed lower-median rank
    {
        int prevIncl = (tid > 0) ? csum[tid - 1] : 0;
        if (ni > 0 && k >= prevIncl && k < csum[tid]) {   // unique owner thread
            int cum = prevIncl, tb = tid * 8;
            #pragma unroll
            for (int i = 0; i < 8; ++i) {
                int c = hist[tid * 8 + i];
                if (k < cum + c) { tb = tid * 8 + i; break; }
                cum += c;
            }
            sh_tb = tb; sh_cb = cum;
        }
    }
    __syncthreads();
    // collect candidates in target bin
    if (ni > 0) {
        int tb = sh_tb;
        #pragma unroll
        for (int i = 0; i < 8; ++i) {
            if (mk[i] > 0.5f && bn[i] == tb) {
                int p = atomicAdd(&sh_candn, 1);
                if (p < 128) cand[p] = ld[i];
            }
        }
    }
    __syncthreads();
    if (tid == 0 && ni > 0) {
        int m = k - sh_cb;
        int cn = (sh_candn < 128) ? sh_candn : 128;
        float best = cand[0];
        for (int i = 0; i < cn; ++i) {
            int rank = 0;
            for (int j = 0; j < cn; ++j)
                rank += (cand[j] < cand[i]) || (cand[j] == cand[i] && j < i);
            if (rank == m) { best = cand[i]; break; }
        }
        medsh = best;
    }
    __syncthreads();
    float med = (ni > 0) ? medsh : 0.0f;
    med = clampf(med, -20.0f, 20.0f);

    float denom = (n > 1.0f) ? n : 1.0f;
    float rv[8];
    float ssum = 0.0f;
    #pragma unroll
    for (int i = 0; i < 8; ++i) { rv[i] = (ld[i] - med) * mk[i]; ssum += rv[i]; }
    float rsum = block_reduce_sum(ssum, red, tid);
    float rm = clampf(rsum / denom, -40.0f, 40.0f);

    float vsum_l = 0.0f;
    #pragma unroll
    for (int i = 0; i < 8; ++i) { float dd = rv[i] - rm; vsum_l += dd * dd * mk[i]; }
    float vsum = block_reduce_sum(vsum_l, red, tid);
    float var = clampf(vsum / denom, 1e-4f, 1e4f);

    float inv_sup = 1.0f / denom;
    #pragma unroll
    for (int i = 0; i < 8; ++i) {
        int t = tid + i * 256;
        size_t o = (size_t)b * T_ + t;
        out[OFF5 + o] = mk[i];
        out[OFF6 + o] = ld[i];
        out[OFF7 + o] = rv[i];
        out[OFF8 + o] = mk[i] * inv_sup;
        out[OFF9 + o] = rm * mk[i];
        rr_ws[o] = rv[i];
    }
    if (tid == 0) {
        out[OFF0 + b] = med;
        out[OFF2 + b] = rm;
        out[OFF3 + b] = var;
        float cov = n * (1.0f / (float)T_);
        out[OFF4 + b] = (cov > 0.05f) ? cov : 0.05f;
        sup_ws[b] = n;
    }
}

// ---------------------------------------------------------------------------
// Kernel 3 (R7 structure, gelu_fast): conv1 gather-GEMM, fp8 MFMA.
//   BM=64 x 512 (two 256-col halves, acc[4][4]). R7 strided fragment loads
//   (4 x 8 B/step, depth-1 prefetch) — measured 76 VGPR, no scratch, 130 µs.
// ---------------------------------------------------------------------------
#define H0S 520
__global__ __launch_bounds__(256, 3) void conv1g_kernel(
    const int* __restrict__ ids, const float* __restrict__ rr,
    const float* __restrict__ emb,
    const float* __restrict__ aux_w, const float* __restrict__ aux_b,
    const unsigned char* __restrict__ W1p, const float* __restrict__ bias1,
    unsigned char* __restrict__ H1buf)
{
    __shared__ __align__(16) unsigned char H0s[66 * H0S];   // 34320 B
    __shared__ int   lid[66];
    __shared__ float lrr[66];

    int tile = blockIdx.x;          // 0..31
    int b    = blockIdx.y;          // 0..31
    int r0   = tile << 6;
    int tid  = threadIdx.x;
    int wave = tid >> 6, lane = tid & 63;
    int q = lane >> 4, m16 = lane & 15;

    if (tid < 66) {
        int t = r0 - 2 + tid;
        bool v = (t >= 0);
        lid[tid] = v ? ids[b * T_ + t] : -1;
        lrr[tid] = v ? rr[(size_t)b * T_ + t] : 0.0f;
    }
    __syncthreads();

    {   // gather hidden0 -> fp8 LDS
        int c4 = tid & 127;
        float4 aw = *(const float4*)(aux_w + c4 * 4);
        float4 ab = *(const float4*)(aux_b + c4 * 4);
        int rbase = tid >> 7;
        for (int j = 0; j < 33; ++j) {
            int row = rbase + j * 2;
            int id = lid[row];
            int word = 0;
            if (id >= 0) {
                float vr = lrr[row];
                float4 e = *(const float4*)(emb + (size_t)id * D_ + c4 * 4);
                word = pk4fp8((e.x + vr * aw.x + ab.x) * SCALE_H0,
                              (e.y + vr * aw.y + ab.y) * SCALE_H0,
                              (e.z + vr * aw.z + ab.z) * SCALE_H0,
                              (e.w + vr * aw.w + ab.w) * SCALE_H0);
            }
            *(int*)(&H0s[row * H0S + c4 * 4]) = word;
        }
    }
    __syncthreads();

    unsigned char* Ob = H1buf + ((size_t)b * 2050 + 2 + r0) * 512;

    #pragma unroll
    for (int nh = 0; nh < 2; ++nh) {
        floatx4 acc[4][4];
        #pragma unroll
        for (int i = 0; i < 4; ++i)
            #pragma unroll
            for (int j = 0; j < 4; ++j)
                acc[i][j] = (floatx4){0.f, 0.f, 0.f, 0.f};

        const long* wp[4];
        #pragma unroll
        for (int nt = 0; nt < 4; ++nt) {
            int ntg = nh * 16 + wave * 4 + nt;
            wp[nt] = (const long*)W1p + ((size_t)ntg * 64 + lane);
        }
        long bfr[2][4];
        #pragma unroll
        for (int nt = 0; nt < 4; ++nt) bfr[0][nt] = wp[nt][0];

        for (int s = 0; s < 48; ++s) {
            int cur = s & 1;
            if (s + 1 < 48) {
                #pragma unroll
                for (int nt = 0; nt < 4; ++nt)
                    bfr[cur ^ 1][nt] = wp[nt][(size_t)(s + 1) * 2048]; // 32*64 longs
            }
            int k1 = s >> 4, ci = s & 15;
            #pragma unroll
            for (int mt = 0; mt < 4; ++mt) {
                long afr = *(const long*)(&H0s[(mt * 16 + m16 + k1) * H0S + ci * 32 + q * 8]);
                #pragma unroll
                for (int nt = 0; nt < 4; ++nt)
                    acc[mt][nt] = __builtin_amdgcn_mfma_f32_16x16x32_fp8_fp8(
                        afr, bfr[cur][nt], acc[mt][nt], 0, 0, 0);
            }
        }

        #pragma unroll
        for (int mt = 0; mt < 4; ++mt) {
            #pragma unroll
            for (int nt = 0; nt < 4; ++nt) {
                int col = nh * 256 + wave * 64 + nt * 16 + m16;
                float bsv = bias1[col];
                #pragma unroll
                for (int r = 0; r < 4; ++r) {
                    int row = mt * 16 + q * 4 + r;
                    float v = gelu_fast(acc[mt][nt][r] * INV1 + bsv) * SCALE_A;
                    Ob[(size_t)row * 512 + col] = f2fp8(v);
                }
            }
        }
    }
}

// ---------------------------------------------------------------------------
// Kernel 4 (R7 structure, gelu_fast): conv2 (fp8 MFMA) + gelu + LN + masked
//   column sums. BM=64 x 512 in two 256-col halves (acc[4][4]); half-0 gelu
//   output stashed in LDS bf16 so LN stats complete after half-1.
// ---------------------------------------------------------------------------
#define H1S 520
#define STS 264         // stash row stride (bf16 elems)
__global__ __launch_bounds__(256, 2) void conv2ln_kernel(
    const unsigned char* __restrict__ H1buf, const unsigned char* __restrict__ W2p,
    const float* __restrict__ bias2,
    const float* __restrict__ ln_g, const float* __restrict__ ln_b,
    const float* __restrict__ maskp,
    float* __restrict__ psum, float* __restrict__ psumsq)
{
    __shared__ __align__(16) unsigned char H1s[66 * H1S];     // 34320 B
    __shared__ __hip_bfloat16 stash[64 * STS];                // 33792 B
    __shared__ float part[64][4][2];                          //  2048 B
    __shared__ float rowsA[64][2];                            //   512 B
    __shared__ float rowst[64][2];                            //   512 B
    __shared__ float colsum[512][2];                          //  4096 B
    __shared__ float mrow[64];

    int tile = blockIdx.x;          // 0..31
    int b    = blockIdx.y;          // 0..31
    int r0   = tile << 6;
    int tid  = threadIdx.x;
    int wave = tid >> 6, lane = tid & 63;
    int q = lane >> 4, m16 = lane & 15;

    // stage A-tile: padded rows r0..r0+65 (coalesced 16B loads)
    const unsigned char* src = H1buf + ((size_t)b * 2050 + r0) * 512;
    for (int g = tid; g < 66 * 32; g += 256) {
        int row = g >> 5, h = g & 31;
        *(float4*)(&H1s[row * H1S + h * 16]) = *(const float4*)(src + (size_t)row * 512 + h * 16);
    }
    if (tid < 64)
        mrow[tid] = clampf(maskp[(size_t)b * T_ + r0 + tid], 0.0f, 1.0f);
    __syncthreads();

    floatx4 acc[4][4];
    float meanv[4][4], rstdv[4][4];

    #pragma unroll
    for (int nh = 0; nh < 2; ++nh) {
        #pragma unroll
        for (int i = 0; i < 4; ++i)
            #pragma unroll
            for (int j = 0; j < 4; ++j)
                acc[i][j] = (floatx4){0.f, 0.f, 0.f, 0.f};

        const long* wp[4];
        #pragma unroll
        for (int nt = 0; nt < 4; ++nt) {
            int ntg = nh * 16 + wave * 4 + nt;
            wp[nt] = (const long*)W2p + ((size_t)ntg * 64 + lane);
        }
        long bfr[2][4];
        #pragma unroll
        for (int nt = 0; nt < 4; ++nt) bfr[0][nt] = wp[nt][0];

        for (int s = 0; s < 48; ++s) {
            int cur = s & 1;
            if (s + 1 < 48) {
                #pragma unroll
                for (int nt = 0; nt < 4; ++nt)
                    bfr[cur ^ 1][nt] = wp[nt][(size_t)(s + 1) * 2048];
            }
            int k2 = s >> 4, ci = s & 15;
            #pragma unroll
            for (int mt = 0; mt < 4; ++mt) {
                long afr = *(const long*)(&H1s[(mt * 16 + m16 + k2) * H1S + ci * 32 + q * 8]);
                #pragma unroll
                for (int nt = 0; nt < 4; ++nt)
                    acc[mt][nt] = __builtin_amdgcn_mfma_f32_16x16x32_fp8_fp8(
                        afr, bfr[cur][nt], acc[mt][nt], 0, 0, 0);
            }
        }

        // gelu in place
        #pragma unroll
        for (int mt = 0; mt < 4; ++mt)
            #pragma unroll
            for (int nt = 0; nt < 4; ++nt) {
                int col = nh * 256 + wave * 64 + nt * 16 + m16;
                float bsv = bias2[col];
                #pragma unroll
                for (int r = 0; r < 4; ++r)
                    acc[mt][nt][r] = gelu_fast(acc[mt][nt][r] * INV2 + bsv);
            }

        // row partials over this half's 256 cols
        #pragma unroll
        for (int mt = 0; mt < 4; ++mt) {
            #pragma unroll
            for (int r = 0; r < 4; ++r) {
                float rs = 0.f, rq = 0.f;
                #pragma unroll
                for (int nt = 0; nt < 4; ++nt) {
                    float v = acc[mt][nt][r];
                    rs += v; rq += v * v;
                }
                rs += __shfl_xor(rs, 1);  rq += __shfl_xor(rq, 1);
                rs += __shfl_xor(rs, 2);  rq += __shfl_xor(rq, 2);
                rs += __shfl_xor(rs, 4);  rq += __shfl_xor(rq, 4);
                rs += __shfl_xor(rs, 8);  rq += __shfl_xor(rq, 8);
                if (m16 == 0) {
                    int row = mt * 16 + q * 4 + r;
                    part[row][wave][0] = rs;
                    part[row][wave][1] = rq;
                }
            }
        }
        if (nh == 0) {
            // stash half-0 gelu output as bf16
            #pragma unroll
            for (int mt = 0; mt < 4; ++mt)
                #pragma unroll
                for (int nt = 0; nt < 4; ++nt) {
                    int cl = wave * 64 + nt * 16 + m16;
                    #pragma unroll
                    for (int r = 0; r < 4; ++r)
                        stash[(mt * 16 + q * 4 + r) * STS + cl] =
                            __float2bfloat16(acc[mt][nt][r]);
                }
            __syncthreads();
            if (tid < 128) {
                int row = tid >> 1, j = tid & 1;
                rowsA[row][j] = part[row][0][j] + part[row][1][j]
                              + part[row][2][j] + part[row][3][j];
            }
            __syncthreads();   // part free for reuse; rowsA stable
        } else {
            __syncthreads();
            if (tid < 128) {
                int row = tid >> 1, j = tid & 1;
                rowst[row][j] = rowsA[row][j] + part[row][0][j] + part[row][1][j]
                              + part[row][2][j] + part[row][3][j];
            }
            __syncthreads();
        }
    }

    // LN stats per row
    #pragma unroll
    for (int mt = 0; mt < 4; ++mt)
        #pragma unroll
        for (int r = 0; r < 4; ++r) {
            int row = mt * 16 + q * 4 + r;
            float m = rowst[row][0] * (1.0f / D_);
            float var = rowst[row][1] * (1.0f / D_) - m * m;
            meanv[mt][r] = m;
            rstdv[mt][r] = rsqrtf((var > 0.0f ? var : 0.0f) + 1e-5f);
        }

    // half-1 columns from live acc
    {
        float cs[4], cq[4];
        #pragma unroll
        for (int nt = 0; nt < 4; ++nt) { cs[nt] = 0.f; cq[nt] = 0.f; }
        #pragma unroll
        for (int mt = 0; mt < 4; ++mt)
            #pragma unroll
            for (int r = 0; r < 4; ++r) {
                int row = mt * 16 + q * 4 + r;
                float mk = mrow[row];
                float m = meanv[mt][r], rs = rstdv[mt][r];
                #pragma unroll
                for (int nt = 0; nt < 4; ++nt) {
                    int col = 256 + wave * 64 + nt * 16 + m16;
                    float xn = ((acc[mt][nt][r] - m) * rs * ln_g[col] + ln_b[col]) * mk;
                    cs[nt] += xn; cq[nt] += xn * xn;
                }
            }
        #pragma unroll
        for (int nt = 0; nt < 4; ++nt) {
            cs[nt] += __shfl_xor(cs[nt], 16);  cq[nt] += __shfl_xor(cq[nt], 16);
            cs[nt] += __shfl_xor(cs[nt], 32);  cq[nt] += __shfl_xor(cq[nt], 32);
        }
        if (lane < 16) {
            #pragma unroll
            for (int nt = 0; nt < 4; ++nt) {
                int col = 256 + wave * 64 + nt * 16 + m16;
                colsum[col][0] = cs[nt];
                colsum[col][1] = cq[nt];
            }
        }
    }
    // half-0 columns from stash
    {
        float cs[4], cq[4];
        #pragma unroll
        for (int nt = 0; nt < 4; ++nt) { cs[nt] = 0.f; cq[nt] = 0.f; }
        #pragma unroll
        for (int mt = 0; mt < 4; ++mt)
            #pragma unroll
            for (int r = 0; r < 4; ++r) {
                int row = mt * 16 + q * 4 + r;
                float mk = mrow[row];
                float m = meanv[mt][r], rs = rstdv[mt][r];
                #pragma unroll
                for (int nt = 0; nt < 4; ++nt) {
                    int cl = wave * 64 + nt * 16 + m16;
                    float v = __bfloat162float(stash[row * STS + cl]);
                    float xn = ((v - m) * rs * ln_g[cl] + ln_b[cl]) * mk;
                    cs[nt] += xn; cq[nt] += xn * xn;
                }
            }
        #pragma unroll
        for (int nt = 0; nt < 4; ++nt) {
            cs[nt] += __shfl_xor(cs[nt], 16);  cq[nt] += __shfl_xor(cq[nt], 16);
            cs[nt] += __shfl_xor(cs[nt], 32);  cq[nt] += __shfl_xor(cq[nt], 32);
        }
        if (lane < 16) {
            #pragma unroll
            for (int nt = 0; nt < 4; ++nt) {
                int col = wave * 64 + nt * 16 + m16;
                colsum[col][0] = cs[nt];
                colsum[col][1] = cq[nt];
            }
        }
    }
    __syncthreads();
    for (int i = tid; i < 512; i += 256) {
        atomicAdd(&psum[(size_t)b * D_ + i], colsum[i][0]);
        atomicAdd(&psumsq[(size_t)b * D_ + i], colsum[i][1]);
    }
}

// ---------------------------------------------------------------------------
// Kernel 5: per-batch MLP head: mean/std -> p1/gelu -> p2/tanh, coeff_norm
// ---------------------------------------------------------------------------
__global__ __launch_bounds__(512) void mlp_kernel(
    const float* __restrict__ psum, const float* __restrict__ psumsq,
    const float* __restrict__ sup_ws,
    const float* __restrict__ p1w, const float* __restrict__ p1b,
    const float* __restrict__ p2w, const float* __restrict__ p2b,
    float* __restrict__ out)
{
    int b = blockIdx.x;
    int d = threadIdx.x;
    __shared__ float h[2 * D_];
    __shared__ float s1[D_];
    __shared__ float red[512];

    float n = sup_ws[b];
    float denom = (n > 1.0f) ? n : 1.0f;
    float S = psum[(size_t)b * D_ + d];
    float Q = psumsq[(size_t)b * D_ + d];
    float mean = S / denom;
    float msum = Q - 2.0f * mean * S + n * mean * mean;
    float arg = msum / denom + 1e-6f;
    float sd = sqrtf((arg > 0.0f) ? arg : 0.0f);
    h[d] = mean;
    h[D_ + d] = sd;
    __syncthreads();

    float z = p1b[d];
    const float4* w4 = (const float4*)(p1w + (size_t)d * (2 * D_));
    for (int jj = 0; jj < 2 * D_ / 4; ++jj) {
        float4 wv = w4[jj];
        z += h[jj * 4 + 0] * wv.x + h[jj * 4 + 1] * wv.y
           + h[jj * 4 + 2] * wv.z + h[jj * 4 + 3] * wv.w;
    }
    s1[d] = gelu_exact(z);
    __syncthreads();

    float z2 = p2b[d];
    const float4* w24 = (const float4*)(p2w + (size_t)d * D_);
    for (int jj = 0; jj < D_ / 4; ++jj) {
        float4 wv = w24[jj];
        z2 += s1[jj * 4 + 0] * wv.x + s1[jj * 4 + 1] * wv.y
            + s1[jj * 4 + 2] * wv.z + s1[jj * 4 + 3] * wv.w;
    }
    float st = tanhf(z2);
    if (!(n > 0.0f)) st = 0.0f;
    out[OFF1 + (size_t)b * D_ + d] = st;

    red[d] = st * st;
    __syncthreads();
    for (int s = 256; s > 0; s >>= 1) {
        if (d < s) red[d] += red[d + s];
        __syncthreads();
    }
    if (d == 0) out[OFF10 + b] = sqrtf(red[0]);
}

// ---------------------------------------------------------------------------
extern "C" void kernel_launch(void* const* d_in, const int* in_sizes, int n_in,
                              void* d_out, int out_size, void* d_ws, size_t ws_size,
                              hipStream_t stream) {
    (void)in_sizes; (void)n_in; (void)out_size; (void)ws_size;
    const int*   unit_ids = (const int*)d_in[0];
    const float* dur      = (const float*)d_in[1];
    const float* mask     = (const float*)d_in[2];
    const float* emb      = (const float*)d_in[3];
    const float* aux_w    = (const float*)d_in[4];
    const float* aux_b    = (const float*)d_in[5];
    const float* conv1_w  = (const float*)d_in[6];
    const float* conv1_b  = (const float*)d_in[7];
    const float* conv2_w  = (const float*)d_in[8];
    const float* conv2_b  = (const float*)d_in[9];
    const float* ln_g     = (const float*)d_in[10];
    const float* ln_b     = (const float*)d_in[11];
    const float* p1_w     = (const float*)d_in[12];
    const float* p1_b     = (const float*)d_in[13];
    const float* p2_w     = (const float*)d_in[14];
    const float* p2_b     = (const float*)d_in[15];
    float* out = (float*)d_out;

    char* ws = (char*)d_ws;
    float*          rr     = (float*)(ws + WS_RR);
    float*          sup    = (float*)(ws + WS_SUP);
    float*          psum   = (float*)(ws + WS_PSUM);
    float*          psumsq = (float*)(ws + WS_PSUMSQ);
    unsigned char*  W1p    = (unsigned char*)(ws + WS_W1P);
    unsigned char*  W2p    = (unsigned char*)(ws + WS_W2P);
    unsigned char*  H1buf  = (unsigned char*)(ws + WS_H1);

    prepack_kernel<<<dim3(384), dim3(256), 0, stream>>>(
        conv1_w, conv2_w, W1p, W2p, psum, H1buf);
    stats_kernel<<<dim3(B_), dim3(256), 0, stream>>>(dur, mask, rr, sup, out);
    conv1g_kernel<<<dim3(32, 32), dim3(256), 0, stream>>>(
        unit_ids, rr, emb, aux_w, aux_b, W1p, conv1_b, H1buf);
    conv2ln_kernel<<<dim3(32, 32), dim3(256), 0, stream>>>(
        H1buf, W2p, conv2_b, ln_g, ln_b, mask, psum, psumsq);
    mlp_kernel<<<dim3(B_), dim3(512), 0, stream>>>(
        psum, psumsq, sup, p1_w, p1_b, p2_w, p2_b, out);
}

// Round 11
// 406.097 us; speedup vs baseline: 1.8304x; 1.8304x over previous
//
#include <hip/hip_runtime.h>
#include <hip/hip_bf16.h>
#include <math.h>

#define B_  32
#define T_  2048
#define D_  512
#define V_  1024
#define K_  3

typedef __attribute__((ext_vector_type(8))) short   short8;
typedef __attribute__((ext_vector_type(4))) float   floatx4;

#define SCALE_H0 256.0f        // hidden0 fp8 scale (conv1 input)
#define SCALE_A  64.0f         // H1 activation fp8 scale (conv2 input)
#define SCALE_W  16.0f         // weight fp8 scale (both convs)
#define INV1 (1.0f/(SCALE_H0*SCALE_W))
#define INV2 (1.0f/(SCALE_A*SCALE_W))

// ---- output flat offsets (elements, fp32) ----
#define OFF0 0        // global_rate      [32]
#define OFF1 32       // summary_state    [32*512]
#define OFF2 16416    // residual_mean    [32]
#define OFF3 16448    // residual_var     [32]
#define OFF4 16480    // coverage         [32]
#define OFF5 16512    // mask             [32*2048]
#define OFF6 82048    // logdur           [32*2048]
#define OFF7 147584   // ref_residual     [32*2048]
#define OFF8 213120   // attn             [32*2048]
#define OFF9 278656   // prompt_role_fit  [32*2048]
#define OFF10 344192  // coeff_norm       [32]

// ---- workspace byte offsets (total 35,553,408 B < proven 36.34 MB) ----
#define WS_RR     0          // fp32 [32][2048]              262144 B
#define WS_SUP    262144     // fp32 [32]                       128 B
#define WS_PSUM   262272     // fp32 [32][512]                65536 B
#define WS_PSUMSQ 327808     // fp32 [32][512]                65536 B
#define WS_W1P    393344     // fp8  frag-packed conv1 w     786432 B
#define WS_W2P    1179776    // fp8  frag-packed conv2 w     786432 B
#define WS_H1     1966208    // fp8  [32][2050][512]       33587200 B

__device__ __forceinline__ float clampf(float v, float lo, float hi) {
    v = (v > lo) ? v : lo;
    return (v < hi) ? v : hi;
}
// NOTE: keep gelu_exact (erff) in the conv epilogues. The inlined tanh-form
// gelu_fast triggered accumulator spill-to-scratch in R8/R9/R10 (FETCH/WRITE
// blew up 10x, conv1g 130 -> 366 us). erff's call structure keeps acc
// register-resident. Do not "optimize" this again without checking WRITE_SIZE.
__device__ __forceinline__ float gelu_exact(float v) {
    return 0.5f * v * (1.0f + erff(v * 0.70710678118654752440f));
}
__device__ __forceinline__ unsigned char f2fp8(float x) {
    int v = __builtin_amdgcn_cvt_pk_fp8_f32(x, x, 0, false);
    return (unsigned char)(v & 0xFF);
}
__device__ __forceinline__ int pk4fp8(float a, float b, float c, float d) {
    int p0 = __builtin_amdgcn_cvt_pk_fp8_f32(a, b, 0, false);
    int p1 = __builtin_amdgcn_cvt_pk_fp8_f32(c, d, 0, false);
    return (p1 << 16) | (p0 & 0xFFFF);
}

__device__ __forceinline__ float block_reduce_sum(float v, float* red, int tid) {
    __syncthreads();
    red[tid] = v;
    __syncthreads();
    for (int s = 128; s > 0; s >>= 1) {
        if (tid < s) red[tid] += red[tid + s];
        __syncthreads();
    }
    float r = red[0];
    __syncthreads();
    return r;
}

// ---------------------------------------------------------------------------
// Kernel 1 (R7): prepack both conv weights into MFMA-fragment-linear fp8
//   layout; zero psum/psumsq and H1 causal pad rows.
//  idx = ((s*32+ntg)*64+lane)*8+e  = w[col][kin][k],  s = k*16+ci,
//    col = ntg*16 + (lane&15), kin = ci*32 + (lane>>4)*8 + e
// ---------------------------------------------------------------------------
__global__ __launch_bounds__(256) void prepack_kernel(
    const float* __restrict__ w1, const float* __restrict__ w2,
    unsigned char* __restrict__ W1p, unsigned char* __restrict__ W2p,
    float* __restrict__ psum, unsigned char* __restrict__ H1buf)
{
    int pid = blockIdx.x * 256 + threadIdx.x;   // 0 .. 98303
    int lane = pid & 63;
    int ntg = (pid >> 6) & 31;
    int ci  = (pid >> 11) & 15;
    int k   = pid >> 15;                        // 0..2
    int col = ntg * 16 + (lane & 15);
    int kin = ci * 32 + (lane >> 4) * 8;

    unsigned char v1[8], v2[8];
    #pragma unroll
    for (int e = 0; e < 8; ++e) {
        size_t src = ((size_t)col * D_ + kin + e) * K_ + k;
        v1[e] = f2fp8(w1[src] * SCALE_W);
        v2[e] = f2fp8(w2[src] * SCALE_W);
    }
    *(double*)(W1p + (size_t)pid * 8) = *(double*)v1;
    *(double*)(W2p + (size_t)pid * 8) = *(double*)v2;

    if (pid < 32768) psum[pid] = 0.0f;          // psum + psumsq contiguous
    if (pid < 32768) {                          // zero 2 causal pad rows/batch
        int b = pid >> 10;
        int r = (pid >> 9) & 1;
        int d = pid & 511;
        H1buf[((size_t)b * 2050 + r) * 512 + d] = 0;
    }
}

// ---------------------------------------------------------------------------
// Kernel 2: per-batch stats — histogram-select exact median + T-wise outputs
// ---------------------------------------------------------------------------
#define NB 2048
#define HLO (-9.3f)
#define HSC ((float)NB / 10.05f)     // range [-9.3, 0.75]
__global__ __launch_bounds__(256) void stats_kernel(
    const float* __restrict__ dur, const float* __restrict__ maskp,
    float* __restrict__ rr_ws, float* __restrict__ sup_ws,
    float* __restrict__ out)
{
    int b = blockIdx.x;
    int tid = threadIdx.x;
    __shared__ int   hist[NB];
    __shared__ int   csum[256];
    __shared__ float red[256];
    __shared__ float cand[128];
    __shared__ float nsh, medsh;
    __shared__ int   sh_tb, sh_cb, sh_candn;

    const float* durb = dur + (size_t)b * T_;
    const float* mkb  = maskp + (size_t)b * T_;

    float ld[8], mk[8];
    int   bn[8];
    float cnt = 0.0f;
    #pragma unroll
    for (int i = 0; i < 8; ++i) hist[tid * 8 + i] = 0;
    __syncthreads();
    #pragma unroll
    for (int i = 0; i < 8; ++i) {
        int t = tid + i * 256;
        float m = clampf(mkb[t], 0.0f, 1.0f);
        float dv = durb[t];
        dv = (dv >= 1e-4f) ? dv : 1e-4f;
        float l = logf(dv) * m;
        ld[i] = l; mk[i] = m;
        int bin = (int)((l - HLO) * HSC);
        bin = (bin < 0) ? 0 : ((bin > NB - 1) ? NB - 1 : bin);
        bn[i] = bin;
        if (m > 0.5f) { cnt += 1.0f; atomicAdd(&hist[bin], 1); }
    }
    float n = block_reduce_sum(cnt, red, tid);   // barriers make hist visible
    if (tid == 0) { nsh = n; sh_candn = 0; medsh = 0.0f; }

    // chunk sums + inclusive scan (Hillis-Steele)
    {
        int cs = 0;
        #pragma unroll
        for (int i = 0; i < 8; ++i) cs += hist[tid * 8 + i];
        csum[tid] = cs;
        __syncthreads();
        for (int off = 1; off < 256; off <<= 1) {
            int v = (tid >= off) ? csum[tid - off] : 0;
            __syncthreads();
            csum[tid] += v;
            __syncthreads();
        }
    }
    int ni = (int)(n + 0.5f);
    int k  = (ni > 0) ? ((ni - 1) >> 1) : 0;     // 0-indexed lower-median rank
    {
        int prevIncl = (tid > 0) ? csum[tid - 1] : 0;
        if (ni > 0 && k >= prevIncl && k < csum[tid]) {   // unique owner thread
            int cum = prevIncl, tb = tid * 8;
            #pragma unroll
            for (int i = 0; i < 8; ++i) {
                int c = hist[tid * 8 + i];
                if (k < cum + c) { tb = tid * 8 + i; break; }
                cum += c;
            }
            sh_tb = tb; sh_cb = cum;
        }
    }
    __syncthreads();
    // collect candidates in target bin
    if (ni > 0) {
        int tb = sh_tb;
        #pragma unroll
        for (int i = 0; i < 8; ++i) {
            if (mk[i] > 0.5f && bn[i] == tb) {
                int p = atomicAdd(&sh_candn, 1);
                if (p < 128) cand[p] = ld[i];
            }
        }
    }
    __syncthreads();
    if (tid == 0 && ni > 0) {
        int m = k - sh_cb;
        int cn = (sh_candn < 128) ? sh_candn : 128;
        float best = cand[0];
        for (int i = 0; i < cn; ++i) {
            int rank = 0;
            for (int j = 0; j < cn; ++j)
                rank += (cand[j] < cand[i]) || (cand[j] == cand[i] && j < i);
            if (rank == m) { best = cand[i]; break; }
        }
        medsh = best;
    }
    __syncthreads();
    float med = (ni > 0) ? medsh : 0.0f;
    med = clampf(med, -20.0f, 20.0f);

    float denom = (n > 1.0f) ? n : 1.0f;
    float rv[8];
    float ssum = 0.0f;
    #pragma unroll
    for (int i = 0; i < 8; ++i) { rv[i] = (ld[i] - med) * mk[i]; ssum += rv[i]; }
    float rsum = block_reduce_sum(ssum, red, tid);
    float rm = clampf(rsum / denom, -40.0f, 40.0f);

    float vsum_l = 0.0f;
    #pragma unroll
    for (int i = 0; i < 8; ++i) { float dd = rv[i] - rm; vsum_l += dd * dd * mk[i]; }
    float vsum = block_reduce_sum(vsum_l, red, tid);
    float var = clampf(vsum / denom, 1e-4f, 1e4f);

    float inv_sup = 1.0f / denom;
    #pragma unroll
    for (int i = 0; i < 8; ++i) {
        int t = tid + i * 256;
        size_t o = (size_t)b * T_ + t;
        out[OFF5 + o] = mk[i];
        out[OFF6 + o] = ld[i];
        out[OFF7 + o] = rv[i];
        out[OFF8 + o] = mk[i] * inv_sup;
        out[OFF9 + o] = rm * mk[i];
        rr_ws[o] = rv[i];
    }
    if (tid == 0) {
        out[OFF0 + b] = med;
        out[OFF2 + b] = rm;
        out[OFF3 + b] = var;
        float cov = n * (1.0f / (float)T_);
        out[OFF4 + b] = (cov > 0.05f) ? cov : 0.05f;
        sup_ws[b] = n;
    }
}

// ---------------------------------------------------------------------------
// Kernel 3 (R7 verbatim): conv1 gather-GEMM, fp8 MFMA. BM=64 x 512 (two
//   256-col halves, acc[4][4]). Strided fragment loads (4 x 8 B/step,
//   depth-1 prefetch). Measured: 76 VGPR, no scratch, 130 us.
// ---------------------------------------------------------------------------
#define H0S 520
__global__ __launch_bounds__(256, 3) void conv1g_kernel(
    const int* __restrict__ ids, const float* __restrict__ rr,
    const float* __restrict__ emb,
    const float* __restrict__ aux_w, const float* __restrict__ aux_b,
    const unsigned char* __restrict__ W1p, const float* __restrict__ bias1,
    unsigned char* __restrict__ H1buf)
{
    __shared__ __align__(16) unsigned char H0s[66 * H0S];   // 34320 B
    __shared__ int   lid[66];
    __shared__ float lrr[66];

    int tile = blockIdx.x;          // 0..31
    int b    = blockIdx.y;          // 0..31
    int r0   = tile << 6;
    int tid  = threadIdx.x;
    int wave = tid >> 6, lane = tid & 63;
    int q = lane >> 4, m16 = lane & 15;

    if (tid < 66) {
        int t = r0 - 2 + tid;
        bool v = (t >= 0);
        lid[tid] = v ? ids[b * T_ + t] : -1;
        lrr[tid] = v ? rr[(size_t)b * T_ + t] : 0.0f;
    }
    __syncthreads();

    {   // gather hidden0 -> fp8 LDS
        int c4 = tid & 127;
        float4 aw = *(const float4*)(aux_w + c4 * 4);
        float4 ab = *(const float4*)(aux_b + c4 * 4);
        int rbase = tid >> 7;
        for (int j = 0; j < 33; ++j) {
            int row = rbase + j * 2;
            int id = lid[row];
            int word = 0;
            if (id >= 0) {
                float vr = lrr[row];
                float4 e = *(const float4*)(emb + (size_t)id * D_ + c4 * 4);
                word = pk4fp8((e.x + vr * aw.x + ab.x) * SCALE_H0,
                              (e.y + vr * aw.y + ab.y) * SCALE_H0,
                              (e.z + vr * aw.z + ab.z) * SCALE_H0,
                              (e.w + vr * aw.w + ab.w) * SCALE_H0);
            }
            *(int*)(&H0s[row * H0S + c4 * 4]) = word;
        }
    }
    __syncthreads();

    unsigned char* Ob = H1buf + ((size_t)b * 2050 + 2 + r0) * 512;

    #pragma unroll
    for (int nh = 0; nh < 2; ++nh) {
        floatx4 acc[4][4];
        #pragma unroll
        for (int i = 0; i < 4; ++i)
            #pragma unroll
            for (int j = 0; j < 4; ++j)
                acc[i][j] = (floatx4){0.f, 0.f, 0.f, 0.f};

        const long* wp[4];
        #pragma unroll
        for (int nt = 0; nt < 4; ++nt) {
            int ntg = nh * 16 + wave * 4 + nt;
            wp[nt] = (const long*)W1p + ((size_t)ntg * 64 + lane);
        }
        long bfr[2][4];
        #pragma unroll
        for (int nt = 0; nt < 4; ++nt) bfr[0][nt] = wp[nt][0];

        for (int s = 0; s < 48; ++s) {
            int cur = s & 1;
            if (s + 1 < 48) {
                #pragma unroll
                for (int nt = 0; nt < 4; ++nt)
                    bfr[cur ^ 1][nt] = wp[nt][(size_t)(s + 1) * 2048]; // 32*64 longs
            }
            int k1 = s >> 4, ci = s & 15;
            #pragma unroll
            for (int mt = 0; mt < 4; ++mt) {
                long afr = *(const long*)(&H0s[(mt * 16 + m16 + k1) * H0S + ci * 32 + q * 8]);
                #pragma unroll
                for (int nt = 0; nt < 4; ++nt)
                    acc[mt][nt] = __builtin_amdgcn_mfma_f32_16x16x32_fp8_fp8(
                        afr, bfr[cur][nt], acc[mt][nt], 0, 0, 0);
            }
        }

        #pragma unroll
        for (int mt = 0; mt < 4; ++mt) {
            #pragma unroll
            for (int nt = 0; nt < 4; ++nt) {
                int col = nh * 256 + wave * 64 + nt * 16 + m16;
                float bsv = bias1[col];
                #pragma unroll
                for (int r = 0; r < 4; ++r) {
                    int row = mt * 16 + q * 4 + r;
                    float v = gelu_exact(acc[mt][nt][r] * INV1 + bsv) * SCALE_A;
                    Ob[(size_t)row * 512 + col] = f2fp8(v);
                }
            }
        }
    }
}

// ---------------------------------------------------------------------------
// Kernel 4 (R7 verbatim): conv2 (fp8 MFMA) + gelu + LN + masked column sums.
//   BM=64 x 512 in two 256-col halves (acc[4][4]); half-0 gelu output stashed
//   in LDS bf16 so LN stats complete after half-1.
// ---------------------------------------------------------------------------
#define H1S 520
#define STS 264         // stash row stride (bf16 elems)
__global__ __launch_bounds__(256, 2) void conv2ln_kernel(
    const unsigned char* __restrict__ H1buf, const unsigned char* __restrict__ W2p,
    const float* __restrict__ bias2,
    const float* __restrict__ ln_g, const float* __restrict__ ln_b,
    const float* __restrict__ maskp,
    float* __restrict__ psum, float* __restrict__ psumsq)
{
    __shared__ __align__(16) unsigned char H1s[66 * H1S];     // 34320 B
    __shared__ __hip_bfloat16 stash[64 * STS];                // 33792 B
    __shared__ float part[64][4][2];                          //  2048 B
    __shared__ float rowsA[64][2];                            //   512 B
    __shared__ float rowst[64][2];                            //   512 B
    __shared__ float colsum[512][2];                          //  4096 B
    __shared__ float mrow[64];

    int tile = blockIdx.x;          // 0..31
    int b    = blockIdx.y;          // 0..31
    int r0   = tile << 6;
    int tid  = threadIdx.x;
    int wave = tid >> 6, lane = tid & 63;
    int q = lane >> 4, m16 = lane & 15;

    // stage A-tile: padded rows r0..r0+65 (coalesced 16B loads)
    const unsigned char* src = H1buf + ((size_t)b * 2050 + r0) * 512;
    for (int g = tid; g < 66 * 32; g += 256) {
        int row = g >> 5, h = g & 31;
        *(float4*)(&H1s[row * H1S + h * 16]) = *(const float4*)(src + (size_t)row * 512 + h * 16);
    }
    if (tid < 64)
        mrow[tid] = clampf(maskp[(size_t)b * T_ + r0 + tid], 0.0f, 1.0f);
    __syncthreads();

    floatx4 acc[4][4];
    float meanv[4][4], rstdv[4][4];

    #pragma unroll
    for (int nh = 0; nh < 2; ++nh) {
        #pragma unroll
        for (int i = 0; i < 4; ++i)
            #pragma unroll
            for (int j = 0; j < 4; ++j)
                acc[i][j] = (floatx4){0.f, 0.f, 0.f, 0.f};

        const long* wp[4];
        #pragma unroll
        for (int nt = 0; nt < 4; ++nt) {
            int ntg = nh * 16 + wave * 4 + nt;
            wp[nt] = (const long*)W2p + ((size_t)ntg * 64 + lane);
        }
        long bfr[2][4];
        #pragma unroll
        for (int nt = 0; nt < 4; ++nt) bfr[0][nt] = wp[nt][0];

        for (int s = 0; s < 48; ++s) {
            int cur = s & 1;
            if (s + 1 < 48) {
                #pragma unroll
                for (int nt = 0; nt < 4; ++nt)
                    bfr[cur ^ 1][nt] = wp[nt][(size_t)(s + 1) * 2048];
            }
            int k2 = s >> 4, ci = s & 15;
            #pragma unroll
            for (int mt = 0; mt < 4; ++mt) {
                long afr = *(const long*)(&H1s[(mt * 16 + m16 + k2) * H1S + ci * 32 + q * 8]);
                #pragma unroll
                for (int nt = 0; nt < 4; ++nt)
                    acc[mt][nt] = __builtin_amdgcn_mfma_f32_16x16x32_fp8_fp8(
                        afr, bfr[cur][nt], acc[mt][nt], 0, 0, 0);
            }
        }

        // gelu in place
        #pragma unroll
        for (int mt = 0; mt < 4; ++mt)
            #pragma unroll
            for (int nt = 0; nt < 4; ++nt) {
                int col = nh * 256 + wave * 64 + nt * 16 + m16;
                float bsv = bias2[col];
                #pragma unroll
                for (int r = 0; r < 4; ++r)
                    acc[mt][nt][r] = gelu_exact(acc[mt][nt][r] * INV2 + bsv);
            }

        // row partials over this half's 256 cols
        #pragma unroll
        for (int mt = 0; mt < 4; ++mt) {
            #pragma unroll
            for (int r = 0; r < 4; ++r) {
                float rs = 0.f, rq = 0.f;
                #pragma unroll
                for (int nt = 0; nt < 4; ++nt) {
                    float v = acc[mt][nt][r];
                    rs += v; rq += v * v;
                }
                rs += __shfl_xor(rs, 1);  rq += __shfl_xor(rq, 1);
                rs += __shfl_xor(rs, 2);  rq += __shfl_xor(rq, 2);
                rs += __shfl_xor(rs, 4);  rq += __shfl_xor(rq, 4);
                rs += __shfl_xor(rs, 8);  rq += __shfl_xor(rq, 8);
                if (m16 == 0) {
                    int row = mt * 16 + q * 4 + r;
                    part[row][wave][0] = rs;
                    part[row][wave][1] = rq;
                }
            }
        }
        if (nh == 0) {
            // stash half-0 gelu output as bf16
            #pragma unroll
            for (int mt = 0; mt < 4; ++mt)
                #pragma unroll
                for (int nt = 0; nt < 4; ++nt) {
                    int cl = wave * 64 + nt * 16 + m16;
                    #pragma unroll
                    for (int r = 0; r < 4; ++r)
                        stash[(mt * 16 + q * 4 + r) * STS + cl] =
                            __float2bfloat16(acc[mt][nt][r]);
                }
            __syncthreads();
            if (tid < 128) {
                int row = tid >> 1, j = tid & 1;
                rowsA[row][j] = part[row][0][j] + part[row][1][j]
                              + part[row][2][j] + part[row][3][j];
            }
            __syncthreads();   // part free for reuse; rowsA stable
        } else {
            __syncthreads();
            if (tid < 128) {
                int row = tid >> 1, j = tid & 1;
                rowst[row][j] = rowsA[row][j] + part[row][0][j] + part[row][1][j]
                              + part[row][2][j] + part[row][3][j];
            }
            __syncthreads();
        }
    }

    // LN stats per row
    #pragma unroll
    for (int mt = 0; mt < 4; ++mt)
        #pragma unroll
        for (int r = 0; r < 4; ++r) {
            int row = mt * 16 + q * 4 + r;
            float m = rowst[row][0] * (1.0f / D_);
            float var = rowst[row][1] * (1.0f / D_) - m * m;
            meanv[mt][r] = m;
            rstdv[mt][r] = rsqrtf((var > 0.0f ? var : 0.0f) + 1e-5f);
        }

    // half-1 columns from live acc
    {
        float cs[4], cq[4];
        #pragma unroll
        for (int nt = 0; nt < 4; ++nt) { cs[nt] = 0.f; cq[nt] = 0.f; }
        #pragma unroll
        for (int mt = 0; mt < 4; ++mt)
            #pragma unroll
            for (int r = 0; r < 4; ++r) {
                int row = mt * 16 + q * 4 + r;
                float mk = mrow[row];
                float m = meanv[mt][r], rs = rstdv[mt][r];
                #pragma unroll
                for (int nt = 0; nt < 4; ++nt) {
                    int col = 256 + wave * 64 + nt * 16 + m16;
                    float xn = ((acc[mt][nt][r] - m) * rs * ln_g[col] + ln_b[col]) * mk;
                    cs[nt] += xn; cq[nt] += xn * xn;
                }
            }
        #pragma unroll
        for (int nt = 0; nt < 4; ++nt) {
            cs[nt] += __shfl_xor(cs[nt], 16);  cq[nt] += __shfl_xor(cq[nt], 16);
            cs[nt] += __shfl_xor(cs[nt], 32);  cq[nt] += __shfl_xor(cq[nt], 32);
        }
        if (lane < 16) {
            #pragma unroll
            for (int nt = 0; nt < 4; ++nt) {
                int col = 256 + wave * 64 + nt * 16 + m16;
                colsum[col][0] = cs[nt];
                colsum[col][1] = cq[nt];
            }
        }
    }
    // half-0 columns from stash
    {
        float cs[4], cq[4];
        #pragma unroll
        for (int nt = 0; nt < 4; ++nt) { cs[nt] = 0.f; cq[nt] = 0.f; }
        #pragma unroll
        for (int mt = 0; mt < 4; ++mt)
            #pragma unroll
            for (int r = 0; r < 4; ++r) {
                int row = mt * 16 + q * 4 + r;
                float mk = mrow[row];
                float m = meanv[mt][r], rs = rstdv[mt][r];
                #pragma unroll
                for (int nt = 0; nt < 4; ++nt) {
                    int cl = wave * 64 + nt * 16 + m16;
                    float v = __bfloat162float(stash[row * STS + cl]);
                    float xn = ((v - m) * rs * ln_g[cl] + ln_b[cl]) * mk;
                    cs[nt] += xn; cq[nt] += xn * xn;
                }
            }
        #pragma unroll
        for (int nt = 0; nt < 4; ++nt) {
            cs[nt] += __shfl_xor(cs[nt], 16);  cq[nt] += __shfl_xor(cq[nt], 16);
            cs[nt] += __shfl_xor(cs[nt], 32);  cq[nt] += __shfl_xor(cq[nt], 32);
        }
        if (lane < 16) {
            #pragma unroll
            for (int nt = 0; nt < 4; ++nt) {
                int col = wave * 64 + nt * 16 + m16;
                colsum[col][0] = cs[nt];
                colsum[col][1] = cq[nt];
            }
        }
    }
    __syncthreads();
    for (int i = tid; i < 512; i += 256) {
        atomicAdd(&psum[(size_t)b * D_ + i], colsum[i][0]);
        atomicAdd(&psumsq[(size_t)b * D_ + i], colsum[i][1]);
    }
}

// ---------------------------------------------------------------------------
// Kernel 5: per-batch MLP head: mean/std -> p1/gelu -> p2/tanh, coeff_norm
// ---------------------------------------------------------------------------
__global__ __launch_bounds__(512) void mlp_kernel(
    const float* __restrict__ psum, const float* __restrict__ psumsq,
    const float* __restrict__ sup_ws,
    const float* __restrict__ p1w, const float* __restrict__ p1b,
    const float* __restrict__ p2w, const float* __restrict__ p2b,
    float* __restrict__ out)
{
    int b = blockIdx.x;
    int d = threadIdx.x;
    __shared__ float h[2 * D_];
    __shared__ float s1[D_];
    __shared__ float red[512];

    float n = sup_ws[b];
    float denom = (n > 1.0f) ? n : 1.0f;
    float S = psum[(size_t)b * D_ + d];
    float Q = psumsq[(size_t)b * D_ + d];
    float mean = S / denom;
    float msum = Q - 2.0f * mean * S + n * mean * mean;
    float arg = msum / denom + 1e-6f;
    float sd = sqrtf((arg > 0.0f) ? arg : 0.0f);
    h[d] = mean;
    h[D_ + d] = sd;
    __syncthreads();

    float z = p1b[d];
    const float4* w4 = (const float4*)(p1w + (size_t)d * (2 * D_));
    for (int jj = 0; jj < 2 * D_ / 4; ++jj) {
        float4 wv = w4[jj];
        z += h[jj * 4 + 0] * wv.x + h[jj * 4 + 1] * wv.y
           + h[jj * 4 + 2] * wv.z + h[jj * 4 + 3] * wv.w;
    }
    s1[d] = gelu_exact(z);
    __syncthreads();

    float z2 = p2b[d];
    const float4* w24 = (const float4*)(p2w + (size_t)d * D_);
    for (int jj = 0; jj < D_ / 4; ++jj) {
        float4 wv = w24[jj];
        z2 += s1[jj * 4 + 0] * wv.x + s1[jj * 4 + 1] * wv.y
            + s1[jj * 4 + 2] * wv.z + s1[jj * 4 + 3] * wv.w;
    }
    float st = tanhf(z2);
    if (!(n > 0.0f)) st = 0.0f;
    out[OFF1 + (size_t)b * D_ + d] = st;

    red[d] = st * st;
    __syncthreads();
    for (int s = 256; s > 0; s >>= 1) {
        if (d < s) red[d] += red[d + s];
        __syncthreads();
    }
    if (d == 0) out[OFF10 + b] = sqrtf(red[0]);
}

// ---------------------------------------------------------------------------
extern "C" void kernel_launch(void* const* d_in, const int* in_sizes, int n_in,
                              void* d_out, int out_size, void* d_ws, size_t ws_size,
                              hipStream_t stream) {
    (void)in_sizes; (void)n_in; (void)out_size; (void)ws_size;
    const int*   unit_ids = (const int*)d_in[0];
    const float* dur      = (const float*)d_in[1];
    const float* mask     = (const float*)d_in[2];
    const float* emb      = (const float*)d_in[3];
    const float* aux_w    = (const float*)d_in[4];
    const float* aux_b    = (const float*)d_in[5];
    const float* conv1_w  = (const float*)d_in[6];
    const float* conv1_b  = (const float*)d_in[7];
    const float* conv2_w  = (const float*)d_in[8];
    const float* conv2_b  = (const float*)d_in[9];
    const float* ln_g     = (const float*)d_in[10];
    const float* ln_b     = (const float*)d_in[11];
    const float* p1_w     = (const float*)d_in[12];
    const float* p1_b     = (const float*)d_in[13];
    const float* p2_w     = (const float*)d_in[14];
    const float* p2_b     = (const float*)d_in[15];
    float* out = (float*)d_out;

    char* ws = (char*)d_ws;
    float*          rr     = (float*)(ws + WS_RR);
    float*          sup    = (float*)(ws + WS_SUP);
    float*          psum   = (float*)(ws + WS_PSUM);
    float*          psumsq = (float*)(ws + WS_PSUMSQ);
    unsigned char*  W1p    = (unsigned char*)(ws + WS_W1P);
    unsigned char*  W2p    = (unsigned char*)(ws + WS_W2P);
    unsigned char*  H1buf  = (unsigned char*)(ws + WS_H1);

    prepack_kernel<<<dim3(384), dim3(256), 0, stream>>>(
        conv1_w, conv2_w, W1p, W2p, psum, H1buf);
    stats_kernel<<<dim3(B_), dim3(256), 0, stream>>>(dur, mask, rr, sup, out);
    conv1g_kernel<<<dim3(32, 32), dim3(256), 0, stream>>>(
        unit_ids, rr, emb, aux_w, aux_b, W1p, conv1_b, H1buf);
    conv2ln_kernel<<<dim3(32, 32), dim3(256), 0, stream>>>(
        H1buf, W2p, conv2_b, ln_g, ln_b, mask, psum, psumsq);
    mlp_kernel<<<dim3(B_), dim3(512), 0, stream>>>(
        psum, psumsq, sup, p1_w, p1_b, p2_w, p2_b, out);
}